// Round 10
// baseline (31.068 us; speedup 1.0000x reference)
//
#include <hip/hip_runtime.h>

#define B 16
#define ENC_T 512
#define ENC_DIM 512
#define DEC_T 2048
#define ROWS 32                      // decoder rows per block
#define NBLK (B * DEC_T / ROWS)      // 1024 blocks

typedef float f32x4 __attribute__((ext_vector_type(4)));  // native vec for NT builtins

// att zeros via hipMemsetAsync (fill path, ~7 TB/s). Kernel writes the out gather
// stream with nontemporal stores (write-once data; keep L2 for enc reuse) and
// scatters the 32768 ones into att.
__global__ __launch_bounds__(512) void out_writer(const float* __restrict__ enc,
                                                  const float* __restrict__ enc_len,
                                                  float* __restrict__ out,
                                                  float* __restrict__ att) {
    __shared__ int   si[ENC_T];      // inclusive cumsum (= end[e])
    __shared__ int   wsum[8];
    __shared__ short sseg[ROWS];

    const int tid = threadIdx.x;     // 0..511
    const int bt0 = blockIdx.x * ROWS;   // first global row of this block
    const int b   = bt0 >> 11;           // / DEC_T (blocks never straddle batches)

    // ---- phase 1: cumsum of batch b durations (wave shfl scan, 8 waves) ----
    int v = (int)enc_len[(size_t)b * ENC_T + tid];   // small ints, exact in f32
    const int lane = tid & 63;
    #pragma unroll
    for (int off = 1; off < 64; off <<= 1) {
        int u = __shfl_up(v, off, 64);
        if (lane >= off) v += u;
    }
    const int w = tid >> 6;
    if (lane == 63) wsum[w] = v;
    __syncthreads();
    int woff = 0;
    for (int k = 0; k < w; ++k) woff += wsum[k];     // <=7 broadcast LDS reads
    si[tid] = v + woff;
    __syncthreads();

    // ---- phase 2: segment ids + att scatter (memset already zeroed att) ----
    if (tid < ROWS) {
        const int t = (bt0 & (DEC_T - 1)) + tid;     // t within batch
        int lo = 0, hi = ENC_T;
        while (lo < hi) {                            // upper_bound: first si[e] > t
            int mid = (lo + hi) >> 1;
            if (si[mid] > t) hi = mid; else lo = mid + 1;
        }
        const int s = (lo < ENC_T) ? lo : -1;
        sseg[tid] = (short)s;
        if (s >= 0)
            __builtin_nontemporal_store(1.0f, &att[(size_t)(bt0 + tid) * ENC_T + s]);
    }
    __syncthreads();

    // ---- phase 3: stream out rows NT, 4 rows per iteration (8 KB contiguous) ----
    const int r = tid >> 7;          // 0..3
    const int j = tid & 127;         // float4 index within row
    const f32x4* encb = (const f32x4*)(enc + (size_t)b * ENC_T * ENC_DIM);
    f32x4* ob = (f32x4*)(out + (size_t)bt0 * ENC_DIM);
    #pragma unroll
    for (int rr = 0; rr < ROWS; rr += 4) {
        const int row = rr + r;
        const int s = sseg[row];
        f32x4 o = (f32x4)(0.0f);
        if (s >= 0) o = encb[s * 128 + j];
        __builtin_nontemporal_store(o, &ob[row * 128 + j]);
    }
}

extern "C" void kernel_launch(void* const* d_in, const int* in_sizes, int n_in,
                              void* d_out, int out_size, void* d_ws, size_t ws_size,
                              hipStream_t stream) {
    const float* enc     = (const float*)d_in[0];   // [B, ENC_T, ENC_DIM]
    const float* enc_len = (const float*)d_in[2];   // [B, ENC_T]

    float* out = (float*)d_out;                          // [B, DEC_T, ENC_DIM]
    float* att = out + (size_t)B * DEC_T * ENC_DIM;      // [B, DEC_T, ENC_T]

    const size_t att_bytes = (size_t)B * DEC_T * ENC_T * sizeof(float);  // 64 MB
    (void)hipMemsetAsync(att, 0, att_bytes, stream);     // fast fill path for the zeros

    hipLaunchKernelGGL(out_writer, dim3(NBLK), dim3(512), 0, stream,
                       enc, enc_len, out, att);
}